// Round 2
// baseline (51.480 us; speedup 1.0000x reference)
//
#include <hip/hip_runtime.h>
#include <hip/hip_bf16.h>

// Problem: 4 embedding-table row gathers.
//   indices: rgap, sgap, pcount, prcount  int32 [128*500] = 64000 each
//   tables:  Wr, Ws, Wp, Wpr              f32   [100*256] (102.4 KB each)
//   output:  concat of 4x [64000, 256] f32 = 65,536,000 floats (262 MB)
//
// Write-BW-bound (fillBuffer demonstrates ~7.1 TB/s pure-write on this chip).
// R1 changes vs R0 (48.3 us, 5.4 TB/s):
//  - exact grid (2000x256 = 512000 threads, 8 j-positions each) -> compile-time
//    trip count, full unroll, 32 independent load->store chains per thread
//    (R0's runtime-trip grid-stride loop serialized on L2 latency).
//  - nontemporal stores: keep the 262 MB write stream from evicting the
//    tables out of each XCD's 4 MB L2.

typedef float f32x4 __attribute__((ext_vector_type(4)));

#define ROWS        64000            // B*S
#define V4_ROW      64               // 256 f32 = 64 float4
#define V4_TAB      (ROWS * V4_ROW)  // 4,096,000 float4 per table
#define NTHREADS    512000           // 2000 blocks * 256
#define ITERS       8                // V4_TAB / NTHREADS, exact

__global__ __launch_bounds__(256) void gather4_kernel(
    const int* __restrict__ i0, const int* __restrict__ i1,
    const int* __restrict__ i2, const int* __restrict__ i3,
    const f32x4* __restrict__ w0, const f32x4* __restrict__ w1,
    const f32x4* __restrict__ w2, const f32x4* __restrict__ w3,
    f32x4* __restrict__ out)
{
    const int* idx[4] = {i0, i1, i2, i3};
    const f32x4* w[4] = {w0, w1, w2, w3};

    const int tid = blockIdx.x * 256 + threadIdx.x;   // 0..511999

#pragma unroll
    for (int k = 0; k < ITERS; ++k) {
        const int j = tid + k * NTHREADS;   // < V4_TAB guaranteed (exact grid)
        const int r = j >> 6;               // row (uniform across a wave)
        const int l = j & 63;               // float4 slot within the row
#pragma unroll
        for (int t = 0; t < 4; ++t) {
            const int id = idx[t][r];                 // small, L1/L2-resident
            const f32x4 v = w[t][id * V4_ROW + l];    // coalesced row read
            __builtin_nontemporal_store(v, &out[(long)t * V4_TAB + j]);
        }
    }
}

extern "C" void kernel_launch(void* const* d_in, const int* in_sizes, int n_in,
                              void* d_out, int out_size, void* d_ws, size_t ws_size,
                              hipStream_t stream) {
    const int* rgap    = (const int*)d_in[0];
    const int* sgap    = (const int*)d_in[1];
    const int* pcount  = (const int*)d_in[2];
    const int* prcount = (const int*)d_in[3];
    const f32x4* Wr  = (const f32x4*)d_in[4];
    const f32x4* Ws  = (const f32x4*)d_in[5];
    const f32x4* Wp  = (const f32x4*)d_in[6];
    const f32x4* Wpr = (const f32x4*)d_in[7];
    f32x4* out = (f32x4*)d_out;

    gather4_kernel<<<2000, 256, 0, stream>>>(
        rgap, sgap, pcount, prcount, Wr, Ws, Wp, Wpr, out);
}

// Round 3
// 47.635 us; speedup vs baseline: 1.0807x; 1.0807x over previous
//
#include <hip/hip_runtime.h>
#include <hip/hip_bf16.h>

// Problem: 4 embedding-table row gathers.
//   indices: rgap, sgap, pcount, prcount  int32 [128*500] = 64000 each
//   tables:  Wr, Ws, Wp, Wpr              f32   [100*256] (102.4 KB each)
//   output:  concat of 4x [64000, 256] f32 = 262 MB
//
// Write-BW-bound. R2 vs R1 (51.5us) / R0 (48.3us):
//  - two-phase: prefetch ALL 32 row indices into registers first (independent
//    4B loads), THEN the table-load->store stream. Removes the 2-hop
//    idx->table serial chain from the store path.
//  - __launch_bounds__(256,4): cap VGPR at 128 so occupancy stays at
//    16 waves/CU (R1's full unroll likely blew VGPRs -> occupancy cliff).
//  - normal stores (nt store in R1 didn't help; fillBuffer gets 7 TB/s
//    through the normal write path).

typedef float f32x4 __attribute__((ext_vector_type(4)));

#define ROWS        64000            // B*S
#define V4_ROW      64               // 256 f32 = 64 float4
#define V4_TAB      (ROWS * V4_ROW)  // 4,096,000 float4 per table
#define NTHREADS    512000           // 2000 blocks * 256
#define ITERS       8                // V4_TAB / NTHREADS, exact

__global__ __launch_bounds__(256, 4) void gather4_kernel(
    const int* __restrict__ i0, const int* __restrict__ i1,
    const int* __restrict__ i2, const int* __restrict__ i3,
    const f32x4* __restrict__ w0, const f32x4* __restrict__ w1,
    const f32x4* __restrict__ w2, const f32x4* __restrict__ w3,
    f32x4* __restrict__ out)
{
    const int* idx[4] = {i0, i1, i2, i3};
    const f32x4* w[4] = {w0, w1, w2, w3};

    const int tid = blockIdx.x * 256 + threadIdx.x;   // 0..511999

    // Phase 1: prefetch all row indices (32 independent 4B loads, all
    // wave-uniform addresses -> broadcast hits in L1/L2).
    int id[ITERS][4];
#pragma unroll
    for (int k = 0; k < ITERS; ++k) {
        const int r = (tid + k * NTHREADS) >> 6;   // row, uniform per wave
#pragma unroll
        for (int t = 0; t < 4; ++t) id[k][t] = idx[t][r];
    }

    // Phase 2: table-row load -> store stream. Loads depend only on the
    // already-resident id[][]; compiler pipelines within the 128-VGPR cap.
#pragma unroll
    for (int k = 0; k < ITERS; ++k) {
        const int j = tid + k * NTHREADS;
        const int l = j & 63;                      // float4 slot within row
#pragma unroll
        for (int t = 0; t < 4; ++t) {
            const f32x4 v = w[t][id[k][t] * V4_ROW + l];  // L2-resident read
            out[(long)t * V4_TAB + j] = v;                 // coalesced 1KiB/wave
        }
    }
}

extern "C" void kernel_launch(void* const* d_in, const int* in_sizes, int n_in,
                              void* d_out, int out_size, void* d_ws, size_t ws_size,
                              hipStream_t stream) {
    const int* rgap    = (const int*)d_in[0];
    const int* sgap    = (const int*)d_in[1];
    const int* pcount  = (const int*)d_in[2];
    const int* prcount = (const int*)d_in[3];
    const f32x4* Wr  = (const f32x4*)d_in[4];
    const f32x4* Ws  = (const f32x4*)d_in[5];
    const f32x4* Wp  = (const f32x4*)d_in[6];
    const f32x4* Wpr = (const f32x4*)d_in[7];
    f32x4* out = (f32x4*)d_out;

    gather4_kernel<<<2000, 256, 0, stream>>>(
        rgap, sgap, pcount, prcount, Wr, Ws, Wp, Wpr, out);
}